// Round 1
// baseline (184.828 us; speedup 1.0000x reference)
//
#include <hip/hip_runtime.h>
#include <stdint.h>

#define NPTS 131072
#define DIM  512
#define KC   512
#define BM   128
#define BK   32
#define NKT  (DIM / BK)   // 16 K-steps

typedef float f32x16 __attribute__((ext_vector_type(16)));
typedef float f32x4  __attribute__((ext_vector_type(4)));
typedef short bf16x8 __attribute__((ext_vector_type(8)));

// round-to-nearest-even fp32 -> bf16 (bit pattern in short)
__device__ __forceinline__ short f2bf(float f) {
  union { float f; unsigned u; } v; v.f = f;
  unsigned r = v.u + 0x7FFFu + ((v.u >> 16) & 1u);
  return (short)(r >> 16);
}

__device__ __forceinline__ bf16x8 pack8(f32x4 a, f32x4 b) {
  bf16x8 p;
  p[0] = f2bf(a.x); p[1] = f2bf(a.y); p[2] = f2bf(a.z); p[3] = f2bf(a.w);
  p[4] = f2bf(b.x); p[5] = f2bf(b.y); p[6] = f2bf(b.z); p[7] = f2bf(b.w);
  return p;
}

__device__ __forceinline__ float sq8(f32x4 a, f32x4 b) {
  return a.x*a.x + a.y*a.y + a.z*a.z + a.w*a.w
       + b.x*b.x + b.y*b.y + b.z*b.z + b.w*b.w;
}

__device__ __forceinline__ void gload_lds16(const short* g, short* l) {
  __builtin_amdgcn_global_load_lds(
      (const __attribute__((address_space(1))) unsigned int*)g,
      (__attribute__((address_space(3))) unsigned int*)l, 16, 0, 0);
}

// ---------------------------------------------------------------------------
// Pre-kernel: clusters fp32 [512][512] -> bf16, tiled per K-step chunk of
// [512 rows][32 cols] with k-slot XOR swizzle (slot ^= (n>>1)&3) so the main
// kernel can stage it with linear global_load_lds. Also c2[n] = ||c_n||^2.
// grid 512 blocks x 64 threads; block n handles cluster row n.
// ---------------------------------------------------------------------------
__global__ void dec_pack(const float* __restrict__ C, short* __restrict__ Bp,
                         float* __restrict__ c2) {
  const int n    = blockIdx.x;
  const int lane = threadIdx.x;          // 0..63; covers 8 floats each
  const float* src = C + (size_t)n * DIM + lane * 8;
  f32x4 v0 = *(const f32x4*)src;
  f32x4 v1 = *(const f32x4*)(src + 4);
  float s = sq8(v0, v1);
  #pragma unroll
  for (int m = 1; m < 64; m <<= 1) s += __shfl_xor(s, m, 64);
  if (lane == 0) c2[n] = s;
  // lane holds source k-slot (kt = lane>>2, c = lane&3, k_local = 8c)
  const int kt = lane >> 2;
  const int sl = (lane & 3) ^ ((n >> 1) & 3);     // stored slot
  *(bf16x8*)(Bp + (size_t)kt * (KC * BK) + n * BK + sl * 8) = pack8(v0, v1);
}

// ---------------------------------------------------------------------------
// Main fused kernel: block tile 128 x 512 (full cluster width), 8 waves
// (2m x 4n), wave tile 64x128 via mfma_f32_32x32x16_bf16, BK=32 dbuf LDS.
// A reg-staged fp32->bf16 with x2 accumulation fused into staging.
// Epilogue: q = rcp(1+d2), block-local row sums, normalize, store fp32.
// ---------------------------------------------------------------------------
__global__ __launch_bounds__(512, 2)
void dec_main(const float* __restrict__ X, const short* __restrict__ Bp,
              const float* __restrict__ c2g, float* __restrict__ out) {
  __shared__ short Abuf[2][BM * BK];   // 2 x 8 KB
  __shared__ short Bbuf[2][KC * BK];   // 2 x 32 KB
  __shared__ float x2arr[BM][4];
  __shared__ float x2tot[BM];
  __shared__ float rowpart[BM][4];
  __shared__ float rowinv[BM];

  const int tid  = threadIdx.x;
  const int lane = tid & 63;
  const int wave = tid >> 6;
  const int wm   = wave >> 2;   // 0..1
  const int wn   = wave & 3;    // 0..3
  const int h    = lane >> 5;   // k-half of MFMA operand
  const int l31  = lane & 31;
  const int row0 = blockIdx.x * BM;

  // A staging role: thread -> (row ar, source k-slot ac), constant across kt
  const int ar = tid >> 2;      // 0..127
  const int ac = tid & 3;       // 0..3
  const float* aptr = X + (size_t)(row0 + ar) * DIM + ac * 8;
  const int aoff = ar * BK + ((ac ^ ((ar >> 1) & 3)) << 3);  // short index

  f32x16 acc[2][4];
  #pragma unroll
  for (int i = 0; i < 2; ++i)
    #pragma unroll
    for (int j = 0; j < 4; ++j)
      acc[i][j] = (f32x16)0.f;

  float x2acc = 0.f;

  // ---- prologue: stage kt=0 into buffer 0 ----
  {
    #pragma unroll
    for (int i = 0; i < 4; ++i) {
      const int chunk = i * 8 + wave;                 // 32 x 1KB chunks
      gload_lds16(Bp + chunk * 512 + lane * 8, &Bbuf[0][chunk * 512 + lane * 8]);
    }
    f32x4 v0 = *(const f32x4*)aptr;
    f32x4 v1 = *(const f32x4*)(aptr + 4);
    x2acc += sq8(v0, v1);
    *(bf16x8*)&Abuf[0][aoff] = pack8(v0, v1);
  }
  __syncthreads();

  // ---- K loop (double-buffered, one barrier per iter) ----
  for (int kt = 0; kt < NKT; ++kt) {
    const int cur = kt & 1;
    f32x4 v0, v1;
    if (kt + 1 < NKT) {
      // issue next B tile (async to LDS) and next A global loads early
      #pragma unroll
      for (int i = 0; i < 4; ++i) {
        const int chunk = i * 8 + wave;
        gload_lds16(Bp + (size_t)(kt + 1) * (KC * BK) + chunk * 512 + lane * 8,
                    &Bbuf[cur ^ 1][chunk * 512 + lane * 8]);
      }
      v0 = *(const f32x4*)(aptr + (kt + 1) * BK);
      v1 = *(const f32x4*)(aptr + (kt + 1) * BK + 4);
    }

    // compute on current buffer: 2 MFMA k-substeps of 16
    #pragma unroll
    for (int ks = 0; ks < 2; ++ks) {
      const int sl = ks * 2 + h;          // source k-slot for this lane
      bf16x8 af[2], bfr[4];
      #pragma unroll
      for (int mt = 0; mt < 2; ++mt) {
        const int r = wm * 64 + mt * 32 + l31;
        af[mt] = *(const bf16x8*)&Abuf[cur][r * BK + ((sl ^ ((r >> 1) & 3)) << 3)];
      }
      #pragma unroll
      for (int nt = 0; nt < 4; ++nt) {
        const int n = wn * 128 + nt * 32 + l31;
        bfr[nt] = *(const bf16x8*)&Bbuf[cur][n * BK + ((sl ^ ((n >> 1) & 3)) << 3)];
      }
      #pragma unroll
      for (int mt = 0; mt < 2; ++mt)
        #pragma unroll
        for (int nt = 0; nt < 4; ++nt)
          acc[mt][nt] = __builtin_amdgcn_mfma_f32_32x32x16_bf16(
              af[mt], bfr[nt], acc[mt][nt], 0, 0, 0);
    }

    if (kt + 1 < NKT) {
      // convert + write next A tile (global latency hidden under MFMA)
      x2acc += sq8(v0, v1);
      *(bf16x8*)&Abuf[cur ^ 1][aoff] = pack8(v0, v1);
    }
    __syncthreads();
  }

  // ---- x2 reduce (4 partials per row) ----
  x2arr[ar][ac] = x2acc;
  __syncthreads();
  if (tid < BM)
    x2tot[tid] = x2arr[tid][0] + x2arr[tid][1] + x2arr[tid][2] + x2arr[tid][3];
  __syncthreads();

  // ---- epilogue: q = 1/(1+d2), block-local row sums, normalize ----
  float c2v[4];
  #pragma unroll
  for (int nt = 0; nt < 4; ++nt) c2v[nt] = c2g[wn * 128 + nt * 32 + l31];

  float rowq[2][16];
  #pragma unroll
  for (int mt = 0; mt < 2; ++mt) {
    #pragma unroll
    for (int r = 0; r < 16; ++r) {
      const int m = wm * 64 + mt * 32 + (r & 3) + 8 * (r >> 2) + 4 * h;
      const float x2m = x2tot[m];
      float s = 0.f;
      #pragma unroll
      for (int nt = 0; nt < 4; ++nt) {
        float d2 = x2m + c2v[nt] - 2.f * acc[mt][nt][r];
        d2 = fmaxf(d2, 0.f);
        float q = __builtin_amdgcn_rcpf(1.f + d2);
        acc[mt][nt][r] = q;          // keep q for the store
        s += q;
      }
      rowq[mt][r] = s;
    }
  }

  // butterfly across the 32 n-lanes (masks < 32 keep the two halves separate)
  #pragma unroll
  for (int msk = 1; msk < 32; msk <<= 1) {
    #pragma unroll
    for (int mt = 0; mt < 2; ++mt)
      #pragma unroll
      for (int r = 0; r < 16; ++r)
        rowq[mt][r] += __shfl_xor(rowq[mt][r], msk, 64);
  }

  if (l31 == 0) {
    #pragma unroll
    for (int mt = 0; mt < 2; ++mt)
      #pragma unroll
      for (int r = 0; r < 16; ++r)
        rowpart[wm * 64 + mt * 32 + (r & 3) + 8 * (r >> 2) + 4 * h][wn] = rowq[mt][r];
  }
  __syncthreads();
  if (tid < BM)
    rowinv[tid] = __builtin_amdgcn_rcpf(rowpart[tid][0] + rowpart[tid][1] +
                                        rowpart[tid][2] + rowpart[tid][3]);
  __syncthreads();

  #pragma unroll
  for (int mt = 0; mt < 2; ++mt) {
    #pragma unroll
    for (int r = 0; r < 16; ++r) {
      const int m = wm * 64 + mt * 32 + (r & 3) + 8 * (r >> 2) + 4 * h;
      const float inv = rowinv[m];
      float* o = out + (size_t)(row0 + m) * KC + wn * 128 + l31;
      #pragma unroll
      for (int nt = 0; nt < 4; ++nt)
        o[nt * 32] = acc[mt][nt][r] * inv;
    }
  }
}

extern "C" void kernel_launch(void* const* d_in, const int* in_sizes, int n_in,
                              void* d_out, int out_size, void* d_ws, size_t ws_size,
                              hipStream_t stream) {
  const float* X = (const float*)d_in[0];   // inputs  [131072, 512] fp32
  const float* C = (const float*)d_in[1];   // clusters [512, 512] fp32
  float* out = (float*)d_out;               // [131072, 512] fp32

  short* Bp = (short*)d_ws;                                   // 512 KB packed bf16 clusters
  float* c2 = (float*)((char*)d_ws + (size_t)KC * DIM * 2);   // 2 KB cluster norms

  dec_pack<<<KC, 64, 0, stream>>>(C, Bp, c2);
  dec_main<<<NPTS / BM, 512, 0, stream>>>(X, Bp, c2, out);
}